// Round 16
// baseline (106.091 us; speedup 1.0000x reference)
//
#include <hip/hip_runtime.h>
#include <math.h>

#define BB 8
#define LL 2048
#define HH 1024
#define JL 64
#define TT 1984          // LL - JL
#define NT2 62           // kA tiles per batch (TT/32)

// workspace layout (float offsets)
#define QT_OFF   0
#define PQ_OFF   (QT_OFF + BB*JL)
#define PDEN_OFF (PQ_OFF + BB*NT2*HH)
#define PMAX_OFF (PDEN_OFF + 512)
#define Q2C_OFF  (PMAX_OFF + 512)
#define QTR_OFF  (Q2C_OFF + BB*HH)            // bf16 query^T [b][h][j], 1 MB
#define QM_OFF   (QTR_OFF + BB*HH*JL/2)       // bf16 qm [b][j][h] = q*wm + wc, 1 MB
#define PWS_OFF  (QM_OFF + BB*JL*HH/2)        // bf16 P [b][t][j], 2 MB

typedef __attribute__((ext_vector_type(8))) short bf16x8;
typedef __attribute__((ext_vector_type(4))) float f32x4;

__device__ inline ushort f2bf(float x) {
  uint u = __float_as_uint(x);
  return (ushort)((u + 0x7FFFu + ((u >> 16) & 1u)) >> 16);
}

// ---- k0: query copy, q_term, qT (bf16 [h][j]), qm (bf16 [j][h]) ----
__global__ __launch_bounds__(256) void k0(const float* __restrict__ enc,
                                          const float* __restrict__ w,
                                          float* __restrict__ out,
                                          float* __restrict__ ws) {
  int j = blockIdx.x, b = blockIdx.y, tid = threadIdx.x;
  const float* qrow = enc + ((size_t)b*LL + j)*HH;
  float4 v = *(const float4*)(qrow + tid*4);
  *(float4*)(out + ((size_t)b*JL + j)*HH + tid*4) = v;
  ushort* qT = (ushort*)(ws + QTR_OFF) + (size_t)b*HH*JL + j;
  qT[(size_t)(tid*4+0)*JL] = f2bf(v.x);
  qT[(size_t)(tid*4+1)*JL] = f2bf(v.y);
  qT[(size_t)(tid*4+2)*JL] = f2bf(v.z);
  qT[(size_t)(tid*4+3)*JL] = f2bf(v.w);
  float4 wmv = *(const float4*)(w + 2*HH + tid*4);
  float4 wcv = *(const float4*)(w + tid*4);
  ushort* qm = (ushort*)(ws + QM_OFF) + ((size_t)b*JL + j)*HH + tid*4;
  *(ushort4*)qm = make_ushort4(f2bf(v.x*wmv.x + wcv.x), f2bf(v.y*wmv.y + wcv.y),
                               f2bf(v.z*wmv.z + wcv.z), f2bf(v.w*wmv.w + wcv.w));
  float4 wq = *(const float4*)(w + HH + tid*4);
  float a = v.x*wq.x + v.y*wq.y + v.z*wq.z + v.w*wq.w;
  #pragma unroll
  for (int o = 32; o > 0; o >>= 1) a += __shfl_xor(a, o);
  __shared__ float red[4];
  if ((tid & 63) == 0) red[tid >> 6] = a;
  __syncthreads();
  if (tid == 0) ws[QT_OFF + b*JL + j] = red[0]+red[1]+red[2]+red[3];
}

// ---- kA: 32-row S-GEMM (MFMA, reg-prefetch staging) -> softmax -> P(bf16)->ws
//      + flash partials ----
__global__ __launch_bounds__(256) void kA(const float* __restrict__ enc,
                                          float* __restrict__ ws) {
  __shared__ ushort ctx_s[32][72];
  __shared__ ushort qm_s[64][72];
  __shared__ ushort P_s[32][72];
  __shared__ float mpart[32][2];
  __shared__ float spart[32][2];
  __shared__ float m_s[32];
  __shared__ float w_s[32];
  const int b = blockIdx.y, bx = blockIdx.x;
  const int t0 = bx * 32;
  const int tid = threadIdx.x;
  const int lane = tid & 63, wvi = tid >> 6;
  const int fr = lane & 15, fg = lane >> 4;
  const int mrow = (wvi & 1) * 16;
  const int nhalf = wvi >> 1;
  const float* ctx = enc + ((size_t)b*LL + JL)*HH;
  const ushort* qmg = (const ushort*)(ws + QM_OFF) + (size_t)b*JL*HH;
  const int cr0 = tid >> 4,        cc0 = (tid & 15)*4;
  const int cr1 = (256+tid) >> 4,  cc1 = cc0;
  const int qr0 = tid >> 3,        qg0 = (tid & 7)*8;
  const int qr1 = (256+tid) >> 3,  qg1 = qg0;
  f32x4 acc[2];
  acc[0] = (f32x4){0.f,0.f,0.f,0.f};
  acc[1] = (f32x4){0.f,0.f,0.f,0.f};
  float4 cvp0, cvp1; uint4 qmp0, qmp1;
  cvp0 = *(const float4*)(ctx + (size_t)(t0 + cr0)*HH + cc0);
  cvp1 = *(const float4*)(ctx + (size_t)(t0 + cr1)*HH + cc1);
  qmp0 = *(const uint4*)(qmg + (size_t)qr0*HH + qg0);
  qmp1 = *(const uint4*)(qmg + (size_t)qr1*HH + qg1);
  for (int h0 = 0; h0 < HH; h0 += 64) {
    *(ushort4*)&ctx_s[cr0][cc0] =
        make_ushort4(f2bf(cvp0.x), f2bf(cvp0.y), f2bf(cvp0.z), f2bf(cvp0.w));
    *(ushort4*)&ctx_s[cr1][cc1] =
        make_ushort4(f2bf(cvp1.x), f2bf(cvp1.y), f2bf(cvp1.z), f2bf(cvp1.w));
    *(uint4*)&qm_s[qr0][qg0] = qmp0;
    *(uint4*)&qm_s[qr1][qg1] = qmp1;
    __syncthreads();
    if (h0 + 64 < HH) {
      const int h1 = h0 + 64;
      cvp0 = *(const float4*)(ctx + (size_t)(t0 + cr0)*HH + h1 + cc0);
      cvp1 = *(const float4*)(ctx + (size_t)(t0 + cr1)*HH + h1 + cc1);
      qmp0 = *(const uint4*)(qmg + (size_t)qr0*HH + h1 + qg0);
      qmp1 = *(const uint4*)(qmg + (size_t)qr1*HH + h1 + qg1);
    }
    #pragma unroll
    for (int kk = 0; kk < 2; ++kk) {
      bf16x8 a = *(const bf16x8*)&ctx_s[mrow + fr][kk*32 + fg*8];
      #pragma unroll
      for (int nf = 0; nf < 2; ++nf) {
        bf16x8 bb = *(const bf16x8*)&qm_s[nhalf*32 + nf*16 + fr][kk*32 + fg*8];
        acc[nf] = __builtin_amdgcn_mfma_f32_16x16x32_bf16(a, bb, acc[nf], 0, 0, 0);
      }
    }
    __syncthreads();
  }
  float qt0 = ws[QT_OFF + (size_t)b*JL + nhalf*32 + fr];
  float qt1 = ws[QT_OFF + (size_t)b*JL + nhalf*32 + 16 + fr];
  float s0r[4], s1r[4], e0r[4], e1r[4], mr[4];
  #pragma unroll
  for (int r = 0; r < 4; ++r) {
    s0r[r] = acc[0][r] + qt0;
    s1r[r] = acc[1][r] + qt1;
    float pm = fmaxf(s0r[r], s1r[r]);
    #pragma unroll
    for (int o = 1; o < 16; o <<= 1) pm = fmaxf(pm, __shfl_xor(pm, o));
    if (fr == 0) mpart[mrow + fg*4 + r][nhalf] = pm;
  }
  __syncthreads();
  #pragma unroll
  for (int r = 0; r < 4; ++r) {
    const int row = mrow + fg*4 + r;
    float m = fmaxf(mpart[row][0], mpart[row][1]);
    mr[r] = m;
    e0r[r] = __expf(s0r[r] - m);
    e1r[r] = __expf(s1r[r] - m);
    float ps = e0r[r] + e1r[r];
    #pragma unroll
    for (int o = 1; o < 16; o <<= 1) ps += __shfl_xor(ps, o);
    if (fr == 0) spart[row][nhalf] = ps;
  }
  __syncthreads();
  #pragma unroll
  for (int r = 0; r < 4; ++r) {
    const int row = mrow + fg*4 + r;
    float inv = 1.f / (spart[row][0] + spart[row][1]);
    P_s[row][nhalf*32 +      fr] = f2bf(e0r[r]*inv);
    P_s[row][nhalf*32 + 16 + fr] = f2bf(e1r[r]*inv);
    if (fr == 0 && nhalf == 0) m_s[row] = mr[r];
  }
  __syncthreads();
  if (tid < 32) {
    float mv2 = m_s[tid];
    float M = mv2;
    #pragma unroll
    for (int o = 1; o < 32; o <<= 1) M = fmaxf(M, __shfl_xor(M, o));
    float wv2 = __expf(mv2 - M);
    w_s[tid] = wv2;
    float den = wv2;
    #pragma unroll
    for (int o = 1; o < 32; o <<= 1) den += __shfl_xor(den, o);
    if (tid == 0) {
      ws[PDEN_OFF + b*NT2 + bx] = den;
      ws[PMAX_OFF + b*NT2 + bx] = M;
    }
  }
  __syncthreads();
  {
    ushort* Pb = (ushort*)(ws + PWS_OFF) + ((size_t)b*TT + t0)*JL;
    int row = tid >> 3, g = tid & 7;
    *(uint4*)(Pb + (size_t)row*JL + g*8) = *(const uint4*)&P_s[row][g*8];
  }
  {
    const int hc = tid * 4;
    const float* ctxb = ctx + (size_t)t0*HH + hc;
    float4 a0 = {0,0,0,0}, a1 = {0,0,0,0};
    #pragma unroll 8
    for (int t = 0; t < 32; t += 2) {
      float w0 = w_s[t], w1 = w_s[t+1];
      float4 v0 = *(const float4*)(ctxb + (size_t)t*HH);
      float4 v1 = *(const float4*)(ctxb + (size_t)(t+1)*HH);
      a0.x += w0*v0.x; a0.y += w0*v0.y; a0.z += w0*v0.z; a0.w += w0*v0.w;
      a1.x += w1*v1.x; a1.y += w1*v1.y; a1.z += w1*v1.z; a1.w += w1*v1.w;
    }
    a0.x += a1.x; a0.y += a1.y; a0.z += a1.z; a0.w += a1.w;
    *(float4*)(ws + PQ_OFF + ((size_t)(b*NT2 + bx))*HH + hc) = a0;
  }
}

// ---- k2 (wide): combine partials with flash rescale -> q2c[b,h] ----
__global__ __launch_bounds__(256) void k2(float* __restrict__ ws) {
  __shared__ float red[8][32][4];
  const int b = blockIdx.y, bx = blockIdx.x, tid = threadIdx.x;
  const int hq = tid & 31, g = tid >> 5;
  const int h4 = bx*32 + hq;
  float M = -1e30f;
  for (int c = 0; c < NT2; ++c) M = fmaxf(M, ws[PMAX_OFF + b*NT2 + c]);
  float den = 0.f;
  for (int c = 0; c < NT2; ++c)
    den += __expf(ws[PMAX_OFF + b*NT2 + c] - M) * ws[PDEN_OFF + b*NT2 + c];
  float inv = 1.f / den;
  float4 a = {0,0,0,0};
  for (int c = g; c < NT2; c += 8) {
    float e = __expf(ws[PMAX_OFF + b*NT2 + c] - M);
    float4 v = *(const float4*)(ws + PQ_OFF + ((size_t)(b*NT2 + c))*HH + h4*4);
    a.x += e*v.x; a.y += e*v.y; a.z += e*v.z; a.w += e*v.w;
  }
  red[g][hq][0] = a.x; red[g][hq][1] = a.y; red[g][hq][2] = a.z; red[g][hq][3] = a.w;
  __syncthreads();
  if (g == 0) {
    #pragma unroll
    for (int k = 1; k < 8; ++k) {
      a.x += red[k][hq][0]; a.y += red[k][hq][1];
      a.z += red[k][hq][2]; a.w += red[k][hq][3];
    }
    a.x *= inv; a.y *= inv; a.z *= inv; a.w *= inv;
    *(float4*)(ws + Q2C_OFF + (size_t)b*HH + h4*4) = a;
  }
}

// ---- kB: PV MFMA (A-frag reg prefetch) -> dbuf LDS bounce -> 4 G slabs
//      (plain cached stores: L2-acked, barrier drain is cheap) ----
__global__ __launch_bounds__(256) void kB(const float* __restrict__ enc,
                                          const float* __restrict__ ws,
                                          float* __restrict__ out) {
  __shared__ ushort P_s[16][72];
  __shared__ float c2q_s[2][16][260];
  const int b = blockIdx.y, t0 = blockIdx.x*16, tid = threadIdx.x;
  const int lane = tid & 63, wvi = tid >> 6;
  const int fr = lane & 15, fg = lane >> 4;
  const ushort* Pb = (const ushort*)(ws + PWS_OFF) + ((size_t)b*TT + t0)*JL;
  if (tid < 128) {
    int row = tid >> 3, g = tid & 7;
    *(uint4*)&P_s[row][g*8] = *(const uint4*)(Pb + (size_t)row*JL + g*8);
  }
  const ushort* qTg = (const ushort*)(ws + QTR_OFF) + (size_t)b*HH*JL;
  const float* ctx = enc + ((size_t)b*LL + JL)*HH;
  float* G = out + (size_t)BB*JL*HH + (size_t)b*TT*4096;
  const int hl = lane * 4;
  // preload A fragments for chunk 0
  bf16x8 af[4][2];
  #pragma unroll
  for (int hh = 0; hh < 4; ++hh)
    #pragma unroll
    for (int kk = 0; kk < 2; ++kk)
      af[hh][kk] = *(const bf16x8*)(qTg + (size_t)(wvi*64 + hh*16 + fr)*JL + kk*32 + fg*8);
  __syncthreads();
  for (int ch = 0; ch < 4; ++ch) {
    const int h0 = ch * 256;
    const int cur = ch & 1;
    float4 ctxr[4];
    #pragma unroll
    for (int p = 0; p < 4; ++p)
      ctxr[p] = *(const float4*)(ctx + (size_t)(t0 + p*4 + wvi)*HH + h0 + hl);
    float4 qcr = *(const float4*)(ws + Q2C_OFF + (size_t)b*HH + h0 + hl);
    f32x4 acc2[4];
    #pragma unroll
    for (int hh = 0; hh < 4; ++hh) acc2[hh] = (f32x4){0.f,0.f,0.f,0.f};
    #pragma unroll
    for (int hh = 0; hh < 4; ++hh)
      #pragma unroll
      for (int kk = 0; kk < 2; ++kk) {
        bf16x8 bb = *(const bf16x8*)&P_s[fr][kk*32 + fg*8];
        acc2[hh] = __builtin_amdgcn_mfma_f32_16x16x32_bf16(af[hh][kk], bb, acc2[hh], 0, 0, 0);
      }
    #pragma unroll
    for (int hh = 0; hh < 4; ++hh)
      *(f32x4*)&c2q_s[cur][fr][wvi*64 + hh*16 + fg*4] = acc2[hh];
    __syncthreads();
    if (ch < 3) {   // prefetch next chunk's A fragments (overlaps store pass)
      const int h1 = h0 + 256;
      #pragma unroll
      for (int hh = 0; hh < 4; ++hh)
        #pragma unroll
        for (int kk = 0; kk < 2; ++kk)
          af[hh][kk] = *(const bf16x8*)(qTg + (size_t)(h1 + wvi*64 + hh*16 + fr)*JL + kk*32 + fg*8);
    }
    #pragma unroll
    for (int p = 0; p < 4; ++p) {
      const int t = p*4 + wvi;
      float4 c2 = *(const float4*)&c2q_s[cur][t][hl];
      float4 cv = ctxr[p];
      float* Gr = G + (size_t)(t0 + t)*4096 + h0 + hl;
      *(float4*)(Gr)        = cv;
      *(float4*)(Gr + 1024) = c2;
      *(float4*)(Gr + 2048) = make_float4(cv.x*c2.x, cv.y*c2.y, cv.z*c2.z, cv.w*c2.w);
      *(float4*)(Gr + 3072) = make_float4(cv.x*qcr.x, cv.y*qcr.y, cv.z*qcr.z, cv.w*qcr.w);
    }
    // dbuf c2q_s: no trailing barrier
  }
}

extern "C" void kernel_launch(void* const* d_in, const int* in_sizes, int n_in,
                              void* d_out, int out_size, void* d_ws, size_t ws_size,
                              hipStream_t stream) {
  const float* enc = (const float*)d_in[0];
  const float* w   = (const float*)d_in[1];
  float* out = (float*)d_out;
  float* ws  = (float*)d_ws;
  k0<<<dim3(JL, BB), 256, 0, stream>>>(enc, w, out, ws);
  kA<<<dim3(NT2, BB), 256, 0, stream>>>(enc, ws);
  k2<<<dim3(8, BB), 256, 0, stream>>>(ws);
  kB<<<dim3(TT/16, BB), 256, 0, stream>>>(enc, ws, out);
}

// Round 17
// 97.358 us; speedup vs baseline: 1.0897x; 1.0897x over previous
//
#include <hip/hip_runtime.h>
#include <math.h>

#define BB 8
#define LL 2048
#define HH 1024
#define JL 64
#define TT 1984          // LL - JL
#define NT2 62           // kA tiles per batch (TT/32)

// workspace layout (float offsets)
#define QT_OFF   0
#define PQ_OFF   (QT_OFF + BB*JL)
#define PDEN_OFF (PQ_OFF + BB*NT2*HH)
#define PMAX_OFF (PDEN_OFF + 512)
#define Q2C_OFF  (PMAX_OFF + 512)
#define QTR_OFF  (Q2C_OFF + BB*HH)            // bf16 query^T [b][h][j], 1 MB
#define QM_OFF   (QTR_OFF + BB*HH*JL/2)       // bf16 qm [b][j][h] = q*wm + wc, 1 MB
#define PWS_OFF  (QM_OFF + BB*JL*HH/2)        // bf16 P [b][t][j], 2 MB

typedef __attribute__((ext_vector_type(8))) short bf16x8;
typedef __attribute__((ext_vector_type(4))) float f32x4;

__device__ inline ushort f2bf(float x) {
  uint u = __float_as_uint(x);
  return (ushort)((u + 0x7FFFu + ((u >> 16) & 1u)) >> 16);
}

__device__ inline void nt_store4(float* p, float a, float b2, float c, float d) {
  f32x4 v = {a, b2, c, d};
  __builtin_nontemporal_store(v, (f32x4*)p);
}

// ---- k0: query copy, q_term, qT (bf16 [h][j]), qm (bf16 [j][h]) ----
__global__ __launch_bounds__(256) void k0(const float* __restrict__ enc,
                                          const float* __restrict__ w,
                                          float* __restrict__ out,
                                          float* __restrict__ ws) {
  int j = blockIdx.x, b = blockIdx.y, tid = threadIdx.x;
  const float* qrow = enc + ((size_t)b*LL + j)*HH;
  float4 v = *(const float4*)(qrow + tid*4);
  *(float4*)(out + ((size_t)b*JL + j)*HH + tid*4) = v;
  ushort* qT = (ushort*)(ws + QTR_OFF) + (size_t)b*HH*JL + j;
  qT[(size_t)(tid*4+0)*JL] = f2bf(v.x);
  qT[(size_t)(tid*4+1)*JL] = f2bf(v.y);
  qT[(size_t)(tid*4+2)*JL] = f2bf(v.z);
  qT[(size_t)(tid*4+3)*JL] = f2bf(v.w);
  float4 wmv = *(const float4*)(w + 2*HH + tid*4);
  float4 wcv = *(const float4*)(w + tid*4);
  ushort* qm = (ushort*)(ws + QM_OFF) + ((size_t)b*JL + j)*HH + tid*4;
  *(ushort4*)qm = make_ushort4(f2bf(v.x*wmv.x + wcv.x), f2bf(v.y*wmv.y + wcv.y),
                               f2bf(v.z*wmv.z + wcv.z), f2bf(v.w*wmv.w + wcv.w));
  float4 wq = *(const float4*)(w + HH + tid*4);
  float a = v.x*wq.x + v.y*wq.y + v.z*wq.z + v.w*wq.w;
  #pragma unroll
  for (int o = 32; o > 0; o >>= 1) a += __shfl_xor(a, o);
  __shared__ float red[4];
  if ((tid & 63) == 0) red[tid >> 6] = a;
  __syncthreads();
  if (tid == 0) ws[QT_OFF + b*JL + j] = red[0]+red[1]+red[2]+red[3];
}

// ---- kA: 32-row S-GEMM (MFMA, reg-prefetch staging) -> softmax -> P(bf16)->ws
//      + flash partials ----
__global__ __launch_bounds__(256) void kA(const float* __restrict__ enc,
                                          float* __restrict__ ws) {
  __shared__ ushort ctx_s[32][72];
  __shared__ ushort qm_s[64][72];
  __shared__ ushort P_s[32][72];
  __shared__ float mpart[32][2];
  __shared__ float spart[32][2];
  __shared__ float m_s[32];
  __shared__ float w_s[32];
  const int b = blockIdx.y, bx = blockIdx.x;
  const int t0 = bx * 32;
  const int tid = threadIdx.x;
  const int lane = tid & 63, wvi = tid >> 6;
  const int fr = lane & 15, fg = lane >> 4;
  const int mrow = (wvi & 1) * 16;
  const int nhalf = wvi >> 1;
  const float* ctx = enc + ((size_t)b*LL + JL)*HH;
  const ushort* qmg = (const ushort*)(ws + QM_OFF) + (size_t)b*JL*HH;
  const int cr0 = tid >> 4,        cc0 = (tid & 15)*4;
  const int cr1 = (256+tid) >> 4,  cc1 = cc0;
  const int qr0 = tid >> 3,        qg0 = (tid & 7)*8;
  const int qr1 = (256+tid) >> 3,  qg1 = qg0;
  f32x4 acc[2];
  acc[0] = (f32x4){0.f,0.f,0.f,0.f};
  acc[1] = (f32x4){0.f,0.f,0.f,0.f};
  float4 cvp0, cvp1; uint4 qmp0, qmp1;
  cvp0 = *(const float4*)(ctx + (size_t)(t0 + cr0)*HH + cc0);
  cvp1 = *(const float4*)(ctx + (size_t)(t0 + cr1)*HH + cc1);
  qmp0 = *(const uint4*)(qmg + (size_t)qr0*HH + qg0);
  qmp1 = *(const uint4*)(qmg + (size_t)qr1*HH + qg1);
  for (int h0 = 0; h0 < HH; h0 += 64) {
    *(ushort4*)&ctx_s[cr0][cc0] =
        make_ushort4(f2bf(cvp0.x), f2bf(cvp0.y), f2bf(cvp0.z), f2bf(cvp0.w));
    *(ushort4*)&ctx_s[cr1][cc1] =
        make_ushort4(f2bf(cvp1.x), f2bf(cvp1.y), f2bf(cvp1.z), f2bf(cvp1.w));
    *(uint4*)&qm_s[qr0][qg0] = qmp0;
    *(uint4*)&qm_s[qr1][qg1] = qmp1;
    __syncthreads();
    if (h0 + 64 < HH) {
      const int h1 = h0 + 64;
      cvp0 = *(const float4*)(ctx + (size_t)(t0 + cr0)*HH + h1 + cc0);
      cvp1 = *(const float4*)(ctx + (size_t)(t0 + cr1)*HH + h1 + cc1);
      qmp0 = *(const uint4*)(qmg + (size_t)qr0*HH + h1 + qg0);
      qmp1 = *(const uint4*)(qmg + (size_t)qr1*HH + h1 + qg1);
    }
    #pragma unroll
    for (int kk = 0; kk < 2; ++kk) {
      bf16x8 a = *(const bf16x8*)&ctx_s[mrow + fr][kk*32 + fg*8];
      #pragma unroll
      for (int nf = 0; nf < 2; ++nf) {
        bf16x8 bb = *(const bf16x8*)&qm_s[nhalf*32 + nf*16 + fr][kk*32 + fg*8];
        acc[nf] = __builtin_amdgcn_mfma_f32_16x16x32_bf16(a, bb, acc[nf], 0, 0, 0);
      }
    }
    __syncthreads();
  }
  float qt0 = ws[QT_OFF + (size_t)b*JL + nhalf*32 + fr];
  float qt1 = ws[QT_OFF + (size_t)b*JL + nhalf*32 + 16 + fr];
  float s0r[4], s1r[4], e0r[4], e1r[4], mr[4];
  #pragma unroll
  for (int r = 0; r < 4; ++r) {
    s0r[r] = acc[0][r] + qt0;
    s1r[r] = acc[1][r] + qt1;
    float pm = fmaxf(s0r[r], s1r[r]);
    #pragma unroll
    for (int o = 1; o < 16; o <<= 1) pm = fmaxf(pm, __shfl_xor(pm, o));
    if (fr == 0) mpart[mrow + fg*4 + r][nhalf] = pm;
  }
  __syncthreads();
  #pragma unroll
  for (int r = 0; r < 4; ++r) {
    const int row = mrow + fg*4 + r;
    float m = fmaxf(mpart[row][0], mpart[row][1]);
    mr[r] = m;
    e0r[r] = __expf(s0r[r] - m);
    e1r[r] = __expf(s1r[r] - m);
    float ps = e0r[r] + e1r[r];
    #pragma unroll
    for (int o = 1; o < 16; o <<= 1) ps += __shfl_xor(ps, o);
    if (fr == 0) spart[row][nhalf] = ps;
  }
  __syncthreads();
  #pragma unroll
  for (int r = 0; r < 4; ++r) {
    const int row = mrow + fg*4 + r;
    float inv = 1.f / (spart[row][0] + spart[row][1]);
    P_s[row][nhalf*32 +      fr] = f2bf(e0r[r]*inv);
    P_s[row][nhalf*32 + 16 + fr] = f2bf(e1r[r]*inv);
    if (fr == 0 && nhalf == 0) m_s[row] = mr[r];
  }
  __syncthreads();
  if (tid < 32) {
    float mv2 = m_s[tid];
    float M = mv2;
    #pragma unroll
    for (int o = 1; o < 32; o <<= 1) M = fmaxf(M, __shfl_xor(M, o));
    float wv2 = __expf(mv2 - M);
    w_s[tid] = wv2;
    float den = wv2;
    #pragma unroll
    for (int o = 1; o < 32; o <<= 1) den += __shfl_xor(den, o);
    if (tid == 0) {
      ws[PDEN_OFF + b*NT2 + bx] = den;
      ws[PMAX_OFF + b*NT2 + bx] = M;
    }
  }
  __syncthreads();
  {
    ushort* Pb = (ushort*)(ws + PWS_OFF) + ((size_t)b*TT + t0)*JL;
    int row = tid >> 3, g = tid & 7;
    *(uint4*)(Pb + (size_t)row*JL + g*8) = *(const uint4*)&P_s[row][g*8];
  }
  {
    const int hc = tid * 4;
    const float* ctxb = ctx + (size_t)t0*HH + hc;
    float4 a0 = {0,0,0,0}, a1 = {0,0,0,0};
    #pragma unroll 8
    for (int t = 0; t < 32; t += 2) {
      float w0 = w_s[t], w1 = w_s[t+1];
      float4 v0 = *(const float4*)(ctxb + (size_t)t*HH);
      float4 v1 = *(const float4*)(ctxb + (size_t)(t+1)*HH);
      a0.x += w0*v0.x; a0.y += w0*v0.y; a0.z += w0*v0.z; a0.w += w0*v0.w;
      a1.x += w1*v1.x; a1.y += w1*v1.y; a1.z += w1*v1.z; a1.w += w1*v1.w;
    }
    a0.x += a1.x; a0.y += a1.y; a0.z += a1.z; a0.w += a1.w;
    *(float4*)(ws + PQ_OFF + ((size_t)(b*NT2 + bx))*HH + hc) = a0;
  }
}

// ---- k2 (wide): combine partials with flash rescale -> q2c[b,h] ----
__global__ __launch_bounds__(256) void k2(float* __restrict__ ws) {
  __shared__ float red[8][32][4];
  const int b = blockIdx.y, bx = blockIdx.x, tid = threadIdx.x;
  const int hq = tid & 31, g = tid >> 5;
  const int h4 = bx*32 + hq;
  float M = -1e30f;
  for (int c = 0; c < NT2; ++c) M = fmaxf(M, ws[PMAX_OFF + b*NT2 + c]);
  float den = 0.f;
  for (int c = 0; c < NT2; ++c)
    den += __expf(ws[PMAX_OFF + b*NT2 + c] - M) * ws[PDEN_OFF + b*NT2 + c];
  float inv = 1.f / den;
  float4 a = {0,0,0,0};
  for (int c = g; c < NT2; c += 8) {
    float e = __expf(ws[PMAX_OFF + b*NT2 + c] - M);
    float4 v = *(const float4*)(ws + PQ_OFF + ((size_t)(b*NT2 + c))*HH + h4*4);
    a.x += e*v.x; a.y += e*v.y; a.z += e*v.z; a.w += e*v.w;
  }
  red[g][hq][0] = a.x; red[g][hq][1] = a.y; red[g][hq][2] = a.z; red[g][hq][3] = a.w;
  __syncthreads();
  if (g == 0) {
    #pragma unroll
    for (int k = 1; k < 8; ++k) {
      a.x += red[k][hq][0]; a.y += red[k][hq][1];
      a.z += red[k][hq][2]; a.w += red[k][hq][3];
    }
    a.x *= inv; a.y *= inv; a.z *= inv; a.w *= inv;
    *(float4*)(ws + Q2C_OFF + (size_t)b*HH + h4*4) = a;
  }
}

// ---- kB: PV MFMA (A-frag reg prefetch) -> dbuf LDS bounce -> 4 G slabs
//      (nontemporal stores: keep L2 for reads) ----
__global__ __launch_bounds__(256) void kB(const float* __restrict__ enc,
                                          const float* __restrict__ ws,
                                          float* __restrict__ out) {
  __shared__ ushort P_s[16][72];
  __shared__ float c2q_s[2][16][260];
  const int b = blockIdx.y, t0 = blockIdx.x*16, tid = threadIdx.x;
  const int lane = tid & 63, wvi = tid >> 6;
  const int fr = lane & 15, fg = lane >> 4;
  const ushort* Pb = (const ushort*)(ws + PWS_OFF) + ((size_t)b*TT + t0)*JL;
  if (tid < 128) {
    int row = tid >> 3, g = tid & 7;
    *(uint4*)&P_s[row][g*8] = *(const uint4*)(Pb + (size_t)row*JL + g*8);
  }
  const ushort* qTg = (const ushort*)(ws + QTR_OFF) + (size_t)b*HH*JL;
  const float* ctx = enc + ((size_t)b*LL + JL)*HH;
  float* G = out + (size_t)BB*JL*HH + (size_t)b*TT*4096;
  const int hl = lane * 4;
  // preload A fragments for chunk 0
  bf16x8 af[4][2];
  #pragma unroll
  for (int hh = 0; hh < 4; ++hh)
    #pragma unroll
    for (int kk = 0; kk < 2; ++kk)
      af[hh][kk] = *(const bf16x8*)(qTg + (size_t)(wvi*64 + hh*16 + fr)*JL + kk*32 + fg*8);
  __syncthreads();
  for (int ch = 0; ch < 4; ++ch) {
    const int h0 = ch * 256;
    const int cur = ch & 1;
    float4 ctxr[4];
    #pragma unroll
    for (int p = 0; p < 4; ++p)
      ctxr[p] = *(const float4*)(ctx + (size_t)(t0 + p*4 + wvi)*HH + h0 + hl);
    float4 qcr = *(const float4*)(ws + Q2C_OFF + (size_t)b*HH + h0 + hl);
    f32x4 acc2[4];
    #pragma unroll
    for (int hh = 0; hh < 4; ++hh) acc2[hh] = (f32x4){0.f,0.f,0.f,0.f};
    #pragma unroll
    for (int hh = 0; hh < 4; ++hh)
      #pragma unroll
      for (int kk = 0; kk < 2; ++kk) {
        bf16x8 bb = *(const bf16x8*)&P_s[fr][kk*32 + fg*8];
        acc2[hh] = __builtin_amdgcn_mfma_f32_16x16x32_bf16(af[hh][kk], bb, acc2[hh], 0, 0, 0);
      }
    #pragma unroll
    for (int hh = 0; hh < 4; ++hh)
      *(f32x4*)&c2q_s[cur][fr][wvi*64 + hh*16 + fg*4] = acc2[hh];
    __syncthreads();
    if (ch < 3) {   // prefetch next chunk's A fragments (overlaps store pass)
      const int h1 = h0 + 256;
      #pragma unroll
      for (int hh = 0; hh < 4; ++hh)
        #pragma unroll
        for (int kk = 0; kk < 2; ++kk)
          af[hh][kk] = *(const bf16x8*)(qTg + (size_t)(h1 + wvi*64 + hh*16 + fr)*JL + kk*32 + fg*8);
    }
    #pragma unroll
    for (int p = 0; p < 4; ++p) {
      const int t = p*4 + wvi;
      float4 c2 = *(const float4*)&c2q_s[cur][t][hl];
      float4 cv = ctxr[p];
      float* Gr = G + (size_t)(t0 + t)*4096 + h0 + hl;
      nt_store4(Gr,        cv.x, cv.y, cv.z, cv.w);
      nt_store4(Gr + 1024, c2.x, c2.y, c2.z, c2.w);
      nt_store4(Gr + 2048, cv.x*c2.x, cv.y*c2.y, cv.z*c2.z, cv.w*c2.w);
      nt_store4(Gr + 3072, cv.x*qcr.x, cv.y*qcr.y, cv.z*qcr.z, cv.w*qcr.w);
    }
    // dbuf c2q_s: no trailing barrier
  }
}

extern "C" void kernel_launch(void* const* d_in, const int* in_sizes, int n_in,
                              void* d_out, int out_size, void* d_ws, size_t ws_size,
                              hipStream_t stream) {
  const float* enc = (const float*)d_in[0];
  const float* w   = (const float*)d_in[1];
  float* out = (float*)d_out;
  float* ws  = (float*)d_ws;
  k0<<<dim3(JL, BB), 256, 0, stream>>>(enc, w, out, ws);
  kA<<<dim3(NT2, BB), 256, 0, stream>>>(enc, ws);
  k2<<<dim3(8, BB), 256, 0, stream>>>(ws);
  kB<<<dim3(TT/16, BB), 256, 0, stream>>>(enc, ws, out);
}